// Round 1
// baseline (24394.423 us; speedup 1.0000x reference)
//
#include <hip/hip_runtime.h>

// ---------------------------------------------------------------------------
// ResRNN: sequential gated residual RNN, B=64, T=2048, D=32, H=256 (fp32).
//
// Tensor-parallel RNN:
//  * 64 RNN wgs = 4 row-groups (16 rows, MFMA M=16) x 16 col-slices (16 cols).
//  * Weight col-slices live in LDS as bf16 MFMA B-fragments (89 KB/CU) --
//    avoids the ~56 B/cyc/CU L2 streaming bound (weight streaming => >=20ms).
//  * h1/h2/h3 exchanged per step through global buffers with agent-scope
//    release/acquire counters; independent MFMA chains hide sync latency.
//  * 4 extra wgs do out = h2@O1 + h3@O2 + bo off the critical path from a
//    depth-64 ring (back-pressure via done[] flags).
// ---------------------------------------------------------------------------

#define T_LEN 2048
#define BATCH 64
#define DIM   32
#define HID   256
#define NRG   4
#define RING  64

typedef short frag_ab __attribute__((ext_vector_type(8)));   // 8 x bf16
typedef float frag_cd __attribute__((ext_vector_type(4)));   // 4 x f32
typedef float float4v __attribute__((ext_vector_type(4)));

#define MFMA16(a, b, c) __builtin_amdgcn_mfma_f32_16x16x32_bf16((a), (b), (c), 0, 0, 0)

// LDS slot bases (1 slot = one K-tile of B-frags = 64 lanes * 16 B = 1 KB)
#define S_W1 0
#define S_U1 1
#define S_W2 9
#define S_U2 17
#define S_W3 25
#define S_U3 33
#define S_V3 41
#define S_G1 49   // 49..56 h1-part, 57..64 h2-part
#define S_G2 65   // 65..72 h1, 73..80 h2, 81..88 h3
#define NSLOT 89
#define LDS_BYTES (NSLOT * 64 * 16)   // 91,136 B

// workspace layout (total ~4.3 MB)
#define H1_OFF   0
#define H1_SZ    (2 * BATCH * HID * 2)
#define H2R_OFF  (H1_OFF + H1_SZ)
#define H2R_SZ   (RING * BATCH * HID * 2)
#define H3R_OFF  (H2R_OFF + H2R_SZ)
#define H3R_SZ   (RING * BATCH * HID * 2)
#define CNT_OFF  (H3R_OFF + H3R_SZ)
#define CNT_SZ   (3 * T_LEN * NRG * 4)
#define DONE_OFF (CNT_OFF + CNT_SZ)
#define DONE_SZ  (T_LEN * NRG * 4)

__device__ __forceinline__ unsigned short f2bf(float f) {
  unsigned u = __builtin_bit_cast(unsigned, f);
  u = (u + 0x7FFFu + ((u >> 16) & 1u)) >> 16;   // RNE
  return (unsigned short)u;
}

__device__ __forceinline__ float fast_tanh(float x) {
  x = fminf(fmaxf(x, -15.f), 15.f);
  float e = __expf(2.f * x);
  return (e - 1.f) / (e + 1.f);
}

__device__ __forceinline__ float fast_sigmoid(float x) {
  x = fminf(fmaxf(x, -30.f), 30.f);
  return 1.f / (1.f + __expf(-x));
}

__device__ __forceinline__ void spin16(unsigned* p) {
  while (__hip_atomic_load(p, __ATOMIC_RELAXED, __HIP_MEMORY_SCOPE_AGENT) < 16u) {}
  __builtin_amdgcn_fence(__ATOMIC_ACQUIRE, "agent");
}

__device__ __forceinline__ void flag_add(unsigned* p, int lane) {
  __builtin_amdgcn_fence(__ATOMIC_RELEASE, "agent");
  if (lane == 0)
    (void)__hip_atomic_fetch_add(p, 1u, __ATOMIC_RELAXED, __HIP_MEMORY_SCOPE_AGENT);
}

__global__ void __launch_bounds__(64, 1)
resrnn_kernel(const float* __restrict__ x,
              const float* __restrict__ W1, const float* __restrict__ U1, const float* __restrict__ b1,
              const float* __restrict__ W2, const float* __restrict__ U2, const float* __restrict__ b2,
              const float* __restrict__ W3, const float* __restrict__ U3, const float* __restrict__ V3,
              const float* __restrict__ b3,
              const float* __restrict__ G1, const float* __restrict__ bg1,
              const float* __restrict__ G2, const float* __restrict__ bg2,
              const float* __restrict__ O1, const float* __restrict__ O2, const float* __restrict__ bo,
              float* __restrict__ out,
              unsigned short* __restrict__ h1buf,   // [2][BATCH][HID]
              unsigned short* __restrict__ h2r,     // [RING][BATCH][HID]
              unsigned short* __restrict__ h3r,     // [RING][BATCH][HID]
              unsigned* __restrict__ cnt,           // [3][T][NRG]
              unsigned* __restrict__ done)          // [T][NRG]
{
  extern __shared__ char smem[];
  frag_ab* wf = (frag_ab*)smem;

  const int lane = (int)threadIdx.x;   // block = 1 wave of 64
  const int quad = lane >> 4;
  const int nn   = lane & 15;
  const int bid  = (int)blockIdx.x;

  if (bid < 64) {
    // ------------------------- RNN workgroup -------------------------
    const int rg = bid & 3;         // row-group; bids {r, r+4, ...} share XCDs {r, r+4}
    const int sl = bid >> 2;        // column-slice
    const int colbase = sl * 16;

    // ---- stage weights into LDS as bf16 B-fragments ----
    {
      const float* mats[9] = { W1, U1, W2, U2, W3, U3, V3, G1, G2 };
      const int    nkt[9]  = { 1, 8, 8, 8, 8, 8, 8, 16, 24 };
      int slot = 0;
      for (int m = 0; m < 9; ++m) {
        const float* W = mats[m];
        for (int kt = 0; kt < nkt[m]; ++kt) {
          frag_ab f;
          #pragma unroll
          for (int j = 0; j < 8; ++j) {
            int k = kt * 32 + quad * 8 + j;
            f[j] = (short)f2bf(W[(size_t)k * HID + colbase + nn]);
          }
          wf[slot * 64 + lane] = f;
          ++slot;
        }
      }
    }

    const float b1l  = b1[colbase + nn];
    const float b2l  = b2[colbase + nn];
    const float b3l  = b3[colbase + nn];
    const float bg1l = bg1[colbase + nn];
    const float bg2l = bg2[colbase + nn];

    frag_ab a1[8], a2[8], a3[8];
    const frag_ab zf = {0,0,0,0,0,0,0,0};
    #pragma unroll
    for (int i = 0; i < 8; ++i) { a1[i] = zf; a2[i] = zf; a3[i] = zf; }
    float h2l[4] = {0.f,0.f,0.f,0.f};
    float h3l[4] = {0.f,0.f,0.f,0.f};
    float z1l[4] = {1.f,1.f,1.f,1.f};
    float z2l[4] = {1.f,1.f,1.f,1.f};

    const float* xrow = x + (size_t)(rg * 16 + nn) * T_LEN * DIM + quad * 8;

    for (int t = 0; t < T_LEN; ++t) {
      // ring back-pressure probe (confirmed below, before any h2r/h3r store;
      // ordering against our stores comes from the cnt-stage-1 acquire fence)
      unsigned* dp = nullptr;
      unsigned  dv = 1u;
      if (t >= RING) {
        dp = done + (size_t)(t - RING) * NRG + rg;
        dv = __hip_atomic_load(dp, __ATOMIC_RELAXED, __HIP_MEMORY_SCOPE_AGENT);
      }

      // ---- stage 1: h1 = tanh(x@W1 + h1@U1 + b1) ----
      frag_cd p1a = {0.f,0.f,0.f,0.f}, p1b = {0.f,0.f,0.f,0.f};
      {
        const float* xp = xrow + (size_t)t * DIM;
        float4v xa = *(const float4v*)xp;
        float4v xb = *(const float4v*)(xp + 4);
        frag_ab xf;
        #pragma unroll
        for (int j = 0; j < 4; ++j) { xf[j] = (short)f2bf(xa[j]); xf[4 + j] = (short)f2bf(xb[j]); }
        p1a = MFMA16(xf, wf[S_W1 * 64 + lane], p1a);
      }
      #pragma unroll
      for (int kt = 0; kt < 4; ++kt) p1a = MFMA16(a1[kt], wf[(S_U1 + kt) * 64 + lane], p1a);
      #pragma unroll
      for (int kt = 4; kt < 8; ++kt) p1b = MFMA16(a1[kt], wf[(S_U1 + kt) * 64 + lane], p1b);
      {
        unsigned short* pp = h1buf + ((size_t)(t & 1) * BATCH + rg * 16 + quad * 4) * HID + colbase + nn;
        #pragma unroll
        for (int rr = 0; rr < 4; ++rr)
          pp[(size_t)rr * HID] = f2bf(fast_tanh(p1a[rr] + p1b[rr] + b1l));
      }
      flag_add(cnt + ((size_t)0 * T_LEN + t) * NRG + rg, lane);

      // overlap: h2@U2 with old h2 frags (independent of h1(t))
      frag_cd p2a = {0.f,0.f,0.f,0.f}, p2b = {0.f,0.f,0.f,0.f};
      #pragma unroll
      for (int kt = 0; kt < 4; ++kt) p2a = MFMA16(a2[kt], wf[(S_U2 + kt) * 64 + lane], p2a);
      #pragma unroll
      for (int kt = 4; kt < 8; ++kt) p2b = MFMA16(a2[kt], wf[(S_U2 + kt) * 64 + lane], p2b);

      // confirm ring slot is free (rarely spins: out-wgs lag ~1 step << 64)
      if (dp && dv == 0u) {
        while (__hip_atomic_load(dp, __ATOMIC_RELAXED, __HIP_MEMORY_SCOPE_AGENT) == 0u) {}
      }

      spin16(cnt + ((size_t)0 * T_LEN + t) * NRG + rg);   // acquire fence here
      {
        const unsigned short* gp = h1buf + ((size_t)(t & 1) * BATCH + rg * 16 + nn) * HID + quad * 8;
        #pragma unroll
        for (int kt = 0; kt < 8; ++kt) a1[kt] = *(const frag_ab*)(gp + kt * 32);
      }

      // ---- stage 2: h2 = z1*tanh(h1@W2 + h2@U2 + b2) + (1-z1)*h2 ----
      #pragma unroll
      for (int kt = 0; kt < 4; ++kt) p2a = MFMA16(a1[kt], wf[(S_W2 + kt) * 64 + lane], p2a);
      #pragma unroll
      for (int kt = 4; kt < 8; ++kt) p2b = MFMA16(a1[kt], wf[(S_W2 + kt) * 64 + lane], p2b);
      #pragma unroll
      for (int rr = 0; rr < 4; ++rr) {
        float c = fast_tanh(p2a[rr] + p2b[rr] + b2l);
        h2l[rr] = z1l[rr] * c + (1.f - z1l[rr]) * h2l[rr];
      }
      {
        unsigned short* pp = h2r + ((size_t)(t & (RING - 1)) * BATCH + rg * 16 + quad * 4) * HID + colbase + nn;
        #pragma unroll
        for (int rr = 0; rr < 4; ++rr) pp[(size_t)rr * HID] = f2bf(h2l[rr]);
      }
      flag_add(cnt + ((size_t)1 * T_LEN + t) * NRG + rg, lane);

      // overlap: h3@U3 (old h3), h1@V3 (new h1), G1 h1-part (new h1)
      frag_cd p3u = {0.f,0.f,0.f,0.f}, p3v = {0.f,0.f,0.f,0.f}, pg1a = {0.f,0.f,0.f,0.f};
      #pragma unroll
      for (int kt = 0; kt < 8; ++kt) p3u = MFMA16(a3[kt], wf[(S_U3 + kt) * 64 + lane], p3u);
      #pragma unroll
      for (int kt = 0; kt < 8; ++kt) p3v = MFMA16(a1[kt], wf[(S_V3 + kt) * 64 + lane], p3v);
      #pragma unroll
      for (int kt = 0; kt < 8; ++kt) pg1a = MFMA16(a1[kt], wf[(S_G1 + kt) * 64 + lane], pg1a);

      spin16(cnt + ((size_t)1 * T_LEN + t) * NRG + rg);
      {
        const unsigned short* gp = h2r + ((size_t)(t & (RING - 1)) * BATCH + rg * 16 + nn) * HID + quad * 8;
        #pragma unroll
        for (int kt = 0; kt < 8; ++kt) a2[kt] = *(const frag_ab*)(gp + kt * 32);
      }

      // ---- stage 3: h3 = z2*tanh(h2@W3 + h3@U3 + h1@V3 + b3) + (1-z2)*h3 ----
      frag_cd p3w = {0.f,0.f,0.f,0.f};
      #pragma unroll
      for (int kt = 0; kt < 8; ++kt) p3w = MFMA16(a2[kt], wf[(S_W3 + kt) * 64 + lane], p3w);
      #pragma unroll
      for (int rr = 0; rr < 4; ++rr) {
        float c = fast_tanh(p3u[rr] + p3v[rr] + p3w[rr] + b3l);
        h3l[rr] = z2l[rr] * c + (1.f - z2l[rr]) * h3l[rr];
      }
      {
        unsigned short* pp = h3r + ((size_t)(t & (RING - 1)) * BATCH + rg * 16 + quad * 4) * HID + colbase + nn;
        #pragma unroll
        for (int rr = 0; rr < 4; ++rr) pp[(size_t)rr * HID] = f2bf(h3l[rr]);
      }
      flag_add(cnt + ((size_t)2 * T_LEN + t) * NRG + rg, lane);

      // overlap: G1 h2-part, G2 h1+h2 parts (independent of h3(t))
      frag_cd pg1b = {0.f,0.f,0.f,0.f}, pg2a = {0.f,0.f,0.f,0.f}, pg2b = {0.f,0.f,0.f,0.f};
      #pragma unroll
      for (int kt = 0; kt < 8; ++kt) pg1b = MFMA16(a2[kt], wf[(S_G1 + 8 + kt) * 64 + lane], pg1b);
      #pragma unroll
      for (int kt = 0; kt < 8; ++kt) pg2a = MFMA16(a1[kt], wf[(S_G2 + kt) * 64 + lane], pg2a);
      #pragma unroll
      for (int kt = 0; kt < 8; ++kt) pg2b = MFMA16(a2[kt], wf[(S_G2 + 8 + kt) * 64 + lane], pg2b);

      spin16(cnt + ((size_t)2 * T_LEN + t) * NRG + rg);
      {
        const unsigned short* gp = h3r + ((size_t)(t & (RING - 1)) * BATCH + rg * 16 + nn) * HID + quad * 8;
        #pragma unroll
        for (int kt = 0; kt < 8; ++kt) a3[kt] = *(const frag_ab*)(gp + kt * 32);
      }

      // ---- gates ----
      frag_cd pg2c = {0.f,0.f,0.f,0.f};
      #pragma unroll
      for (int kt = 0; kt < 8; ++kt) pg2c = MFMA16(a3[kt], wf[(S_G2 + 16 + kt) * 64 + lane], pg2c);
      #pragma unroll
      for (int rr = 0; rr < 4; ++rr) {
        float z1n = fast_sigmoid(pg1a[rr] + pg1b[rr] + bg1l);
        float z2n = fast_sigmoid(pg2a[rr] + pg2b[rr] + pg2c[rr] + bg2l);
        z1l[rr] = z1n * z2n;
        z2l[rr] = z2n;
      }
    }
  } else {
    // --------------------- output-projection workgroup ---------------------
    const int rg = bid - 64;
    {
      const float* mats[2] = { O1, O2 };
      for (int m = 0; m < 2; ++m)
        for (int nt = 0; nt < 2; ++nt)
          for (int kt = 0; kt < 8; ++kt) {
            frag_ab f;
            #pragma unroll
            for (int j = 0; j < 8; ++j) {
              int k = kt * 32 + quad * 8 + j;
              f[j] = (short)f2bf(mats[m][(size_t)k * DIM + nt * 16 + nn]);
            }
            wf[(m * 16 + nt * 8 + kt) * 64 + lane] = f;
          }
    }
    const float bo0 = bo[nn];
    const float bo1 = bo[16 + nn];

    for (int t = 0; t < T_LEN; ++t) {
      spin16(cnt + ((size_t)2 * T_LEN + t) * NRG + rg);  // h3 flag; h2 visible transitively
      frag_ab a2[8], a3[8];
      {
        const unsigned short* g2p = h2r + ((size_t)(t & (RING - 1)) * BATCH + rg * 16 + nn) * HID + quad * 8;
        const unsigned short* g3p = h3r + ((size_t)(t & (RING - 1)) * BATCH + rg * 16 + nn) * HID + quad * 8;
        #pragma unroll
        for (int kt = 0; kt < 8; ++kt) {
          a2[kt] = *(const frag_ab*)(g2p + kt * 32);
          a3[kt] = *(const frag_ab*)(g3p + kt * 32);
        }
      }
      frag_cd o0 = {0.f,0.f,0.f,0.f}, o1 = {0.f,0.f,0.f,0.f};
      #pragma unroll
      for (int kt = 0; kt < 8; ++kt) {
        o0 = MFMA16(a2[kt], wf[(0 * 16 + 0 * 8 + kt) * 64 + lane], o0);
        o1 = MFMA16(a2[kt], wf[(0 * 16 + 1 * 8 + kt) * 64 + lane], o1);
        o0 = MFMA16(a3[kt], wf[(1 * 16 + 0 * 8 + kt) * 64 + lane], o0);
        o1 = MFMA16(a3[kt], wf[(1 * 16 + 1 * 8 + kt) * 64 + lane], o1);
      }
      #pragma unroll
      for (int rr = 0; rr < 4; ++rr) {
        float* op = out + ((size_t)(rg * 16 + quad * 4 + rr) * T_LEN + t) * DIM;
        op[nn]      = o0[rr] + bo0;
        op[16 + nn] = o1[rr] + bo1;
      }
      __builtin_amdgcn_fence(__ATOMIC_RELEASE, "agent");   // orders our ring READS too
      if (lane == 0)
        __hip_atomic_store(done + (size_t)t * NRG + rg, 1u,
                           __ATOMIC_RELAXED, __HIP_MEMORY_SCOPE_AGENT);
    }
  }
}

extern "C" void kernel_launch(void* const* d_in, const int* in_sizes, int n_in,
                              void* d_out, int out_size, void* d_ws, size_t ws_size,
                              hipStream_t stream)
{
  (void)in_sizes; (void)n_in; (void)out_size; (void)ws_size;

  const float* x   = (const float*)d_in[0];
  const float* W1  = (const float*)d_in[1];
  const float* U1  = (const float*)d_in[2];
  const float* b1  = (const float*)d_in[3];
  const float* W2  = (const float*)d_in[4];
  const float* U2  = (const float*)d_in[5];
  const float* b2  = (const float*)d_in[6];
  const float* W3  = (const float*)d_in[7];
  const float* U3  = (const float*)d_in[8];
  const float* V3  = (const float*)d_in[9];
  const float* b3  = (const float*)d_in[10];
  const float* G1  = (const float*)d_in[11];
  const float* bg1 = (const float*)d_in[12];
  const float* G2  = (const float*)d_in[13];
  const float* bg2 = (const float*)d_in[14];
  const float* O1  = (const float*)d_in[15];
  const float* O2  = (const float*)d_in[16];
  const float* bo  = (const float*)d_in[17];

  char* ws = (char*)d_ws;
  unsigned short* h1buf = (unsigned short*)(ws + H1_OFF);
  unsigned short* h2r   = (unsigned short*)(ws + H2R_OFF);
  unsigned short* h3r   = (unsigned short*)(ws + H3R_OFF);
  unsigned*       cnt   = (unsigned*)(ws + CNT_OFF);
  unsigned*       done  = (unsigned*)(ws + DONE_OFF);

  // zero the sync counters (ws is re-poisoned to 0xAA before every launch)
  hipMemsetAsync(cnt, 0, CNT_SZ + DONE_SZ, stream);

  // opt in to >64KB dynamic LDS (91,136 B); ignore failure on toolchains
  // that allow it by default
  (void)hipFuncSetAttribute((const void*)resrnn_kernel,
                            hipFuncAttributeMaxDynamicSharedMemorySize, LDS_BYTES);

  resrnn_kernel<<<dim3(68), dim3(64), LDS_BYTES, stream>>>(
      x, W1, U1, b1, W2, U2, b2, W3, U3, V3, b3,
      G1, bg1, G2, bg2, O1, O2, bo,
      (float*)d_out, h1buf, h2r, h3r, cnt, done);
}